// Round 5
// baseline (415.827 us; speedup 1.0000x reference)
//
#include <hip/hip_runtime.h>
#include <hip/hip_cooperative_groups.h>

namespace cg = cooperative_groups;

// Backward slice from the single output node n-1 (see round 2/3 notes):
//   D = {n-1} U in-neighbors(n-1) (~34 nodes); layer-2 agg needs only edges
//   into D (~1100); deg needed only for their sources U D.
// ONE cooperative kernel, phases separated by grid.sync():
//   P0 zero bitmaps/cnts (deg zeroed lazily at first bm2-mark)
//   P1 scan dst: edges into n-1 -> S1 multiset, bm1/Dlist (dedup'd)
//   P2 scan dst: edges into bm1 -> L2 packed list, bm2 |= sources U D
//   P3 scan dst: deg[d]++ for d in bm2 (~37k atomics)
//   P4 block 0: LDS hash d->idx, per-edge msg accumulate, g rows, agg, FC.
// Round-4 postmortem: 512 blocks = 22% occupancy starved the latency-bound
// scans (240us). Grid now sized from the occupancy API (8 blocks/CU -> 2048).

#define S1CAP 2048
#define DCAP  192
#define L2CAP 65536
#define HASHSZ 512

__global__ __launch_bounds__(256)
void k_fused(const float* __restrict__ x, const int* __restrict__ src,
             const int* __restrict__ dst, const float* __restrict__ W1,
             const float* __restrict__ b1, const float* __restrict__ W2,
             const float* __restrict__ b2, const float* __restrict__ Wfc,
             const float* __restrict__ bfc, int E, int n,
             int* __restrict__ deg, unsigned* __restrict__ bm1,
             unsigned* __restrict__ bm2, int* __restrict__ cnts,
             int* __restrict__ S1, int* __restrict__ Dlist,
             unsigned long long* __restrict__ L2, float* __restrict__ out) {
    cg::grid_group grid = cg::this_grid();
    const int tid = threadIdx.x;
    const int gtid = blockIdx.x * blockDim.x + tid;
    const int gsz = gridDim.x * blockDim.x;
    const int E4 = E >> 2;
    const int tgt = n - 1;

    // ---- P0: zero bitmaps + counters (deg is zeroed lazily) ----
    const int bmW = (n + 31) >> 5;
    for (int i = gtid; i < bmW; i += gsz) { bm1[i] = 0u; bm2[i] = 0u; }
    if (gtid == 0) { cnts[0] = 0; cnts[1] = 0; cnts[2] = 0; }
    grid.sync();

    // ---- P1: edges into tgt ----
    for (int i = gtid; i < E4; i += gsz) {
        int4 d4 = ((const int4*)dst)[i];
        int dd[4] = {d4.x, d4.y, d4.z, d4.w};
#pragma unroll
        for (int k = 0; k < 4; ++k) {
            if (dd[k] == tgt) {
                int s = src[i * 4 + k];
                int p = atomicAdd(&cnts[0], 1);
                if (p < S1CAP) S1[p] = s;
                unsigned bit = 1u << (s & 31);
                unsigned old = atomicOr(&bm1[s >> 5], bit);
                if (!(old & bit)) {
                    int q = atomicAdd(&cnts[1], 1);
                    if (q < DCAP) Dlist[q] = s;
                }
            }
        }
    }
    if (gtid == 0) {
        for (int e = E4 * 4; e < E; ++e) {
            if (dst[e] == tgt) {
                int s = src[e];
                int p = atomicAdd(&cnts[0], 1);
                if (p < S1CAP) S1[p] = s;
                unsigned bit = 1u << (s & 31);
                unsigned old = atomicOr(&bm1[s >> 5], bit);
                if (!(old & bit)) {
                    int q = atomicAdd(&cnts[1], 1);
                    if (q < DCAP) Dlist[q] = s;
                }
            }
        }
        unsigned bit = 1u << (tgt & 31);
        unsigned old = atomicOr(&bm1[tgt >> 5], bit);
        if (!(old & bit)) {
            int q = atomicAdd(&cnts[1], 1);
            if (q < DCAP) Dlist[q] = tgt;
        }
    }
    grid.sync();

    // ---- P2: edges into D; bm2 = {their sources} U D; lazy deg zero ----
    int cntD = cnts[1]; if (cntD > DCAP) cntD = DCAP;
    for (int i = gtid; i < cntD; i += gsz) {
        int d = Dlist[i];
        unsigned bit = 1u << (d & 31);
        unsigned old = atomicOr(&bm2[d >> 5], bit);
        if (!(old & bit)) deg[d] = 0;
    }
    for (int i = gtid; i < E4; i += gsz) {
        int4 d4 = ((const int4*)dst)[i];
        int dd[4] = {d4.x, d4.y, d4.z, d4.w};
#pragma unroll
        for (int k = 0; k < 4; ++k) {
            int d = dd[k];
            if ((bm1[d >> 5] >> (d & 31)) & 1u) {
                int s = src[i * 4 + k];
                int p = atomicAdd(&cnts[2], 1);
                if (p < L2CAP)
                    L2[p] = ((unsigned long long)(unsigned)d << 32) | (unsigned)s;
                unsigned bit = 1u << (s & 31);
                unsigned old = atomicOr(&bm2[s >> 5], bit);
                if (!(old & bit)) deg[s] = 0;
            }
        }
    }
    if (gtid == 0) {
        for (int e = E4 * 4; e < E; ++e) {
            int d = dst[e];
            if ((bm1[d >> 5] >> (d & 31)) & 1u) {
                int s = src[e];
                int p = atomicAdd(&cnts[2], 1);
                if (p < L2CAP)
                    L2[p] = ((unsigned long long)(unsigned)d << 32) | (unsigned)s;
                unsigned bit = 1u << (s & 31);
                unsigned old = atomicOr(&bm2[s >> 5], bit);
                if (!(old & bit)) deg[s] = 0;
            }
        }
    }
    grid.sync();

    // ---- P3: deg for bm2 nodes ----
    for (int i = gtid; i < E4; i += gsz) {
        int4 d4 = ((const int4*)dst)[i];
        int dd[4] = {d4.x, d4.y, d4.z, d4.w};
#pragma unroll
        for (int k = 0; k < 4; ++k) {
            int d = dd[k];
            if ((bm2[d >> 5] >> (d & 31)) & 1u) atomicAdd(&deg[d], 1);
        }
    }
    if (gtid == 0) {
        for (int e = E4 * 4; e < E; ++e) {
            int d = dst[e];
            if ((bm2[d >> 5] >> (d & 31)) & 1u) atomicAdd(&deg[d], 1);
        }
    }
    grid.sync();

    // ---- P4: finisher, block 0 only ----
    if (blockIdx.x != 0) return;
    __shared__ int hKey[HASHSZ];
    __shared__ int hVal[HASHSZ];
    __shared__ int sD[DCAP];
    __shared__ float s1D[DCAP];
    __shared__ float gD[DCAP][8];
    __shared__ float sW1[16], sb1[16], sW2[128], agg[8];

    int cnt1 = cnts[0]; if (cnt1 > S1CAP) cnt1 = S1CAP;
    cntD = cnts[1]; if (cntD > DCAP) cntD = DCAP;
    int cnt2 = cnts[2]; if (cnt2 > L2CAP) cnt2 = L2CAP;

    for (int i = tid; i < HASHSZ; i += 256) hKey[i] = -1;
    for (int i = tid; i < cntD; i += 256) { sD[i] = Dlist[i]; s1D[i] = 0.f; }
    if (tid < 16) { sW1[tid] = W1[tid]; sb1[tid] = b1[tid]; }
    if (tid < 128) sW2[tid] = W2[tid];
    if (tid < 8) agg[tid] = 0.f;
    __syncthreads();
    // build hash d -> index
    for (int i = tid; i < cntD; i += 256) {
        int d = sD[i];
        int h = d & (HASHSZ - 1);
        while (true) {
            int prev = atomicCAS(&hKey[h], -1, d);
            if (prev == -1 || prev == d) { hVal[h] = i; break; }
            h = (h + 1) & (HASHSZ - 1);
        }
    }
    __syncthreads();
    // per-edge messages -> LDS bins (independent pipelined scattered loads)
    for (int e = tid; e < cnt2; e += 256) {
        unsigned long long v = L2[e];
        int s = (int)(v & 0xffffffffu);
        int d = (int)(v >> 32);
        float msg = x[s] * rsqrtf((float)(deg[s] + 1));
        int h = d & (HASHSZ - 1);
        while (hKey[h] != d) h = (h + 1) & (HASHSZ - 1);
        atomicAdd(&s1D[hVal[h]], msg);
    }
    __syncthreads();
    // per-D-node: h1 -> g row (g = dinv * (h1 @ W2))
    for (int di = tid; di < cntD; di += 256) {
        int d = sD[di];
        float dv = rsqrtf((float)(deg[d] + 1));
        float t = dv * (s1D[di] + x[d] * dv);   // + self-loop term
        float g8[8] = {0, 0, 0, 0, 0, 0, 0, 0};
#pragma unroll
        for (int c = 0; c < 16; ++c) {
            float h1 = fmaxf(fmaf(t, sW1[c], sb1[c]), 0.f);
#pragma unroll
            for (int j = 0; j < 8; ++j) g8[j] = fmaf(h1, sW2[c * 8 + j], g8[j]);
        }
#pragma unroll
        for (int j = 0; j < 8; ++j) gD[di][j] = dv * g8[j];
    }
    __syncthreads();
    // layer-2 aggregation at tgt over the S1 multiset
    for (int idx = tid; idx < cnt1 * 8; idx += 256) {
        int p = idx >> 3, j = idx & 7;
        int s = S1[p];
        int h = s & (HASHSZ - 1);
        while (hKey[h] != s) h = (h + 1) & (HASHSZ - 1);
        atomicAdd(&agg[j], gD[hVal[h]][j]);
    }
    __syncthreads();
    if (tid == 0) {
        int h = tgt & (HASHSZ - 1);
        while (hKey[h] != tgt) h = (h + 1) & (HASHSZ - 1);
        int it = hVal[h];
        float dv = rsqrtf((float)(deg[tgt] + 1));
        float o = 0.f;
#pragma unroll
        for (int j = 0; j < 8; ++j)
            o += fmaxf(fmaf(dv, agg[j] + gD[it][j], b2[j]), 0.f) * Wfc[j];
        out[0] = o + bfc[0];
    }
}

extern "C" void kernel_launch(void* const* d_in, const int* in_sizes, int n_in,
                              void* d_out, int out_size, void* d_ws, size_t ws_size,
                              hipStream_t stream) {
    const float* x   = (const float*)d_in[0];
    const int*   ei  = (const int*)d_in[1];
    const float* W1  = (const float*)d_in[2];
    const float* b1  = (const float*)d_in[3];
    const float* W2  = (const float*)d_in[4];
    const float* b2  = (const float*)d_in[5];
    const float* Wfc = (const float*)d_in[6];
    const float* bfc = (const float*)d_in[7];
    float* out = (float*)d_out;

    int n = in_sizes[0];
    int E = in_sizes[1] / 2;
    const int* src = ei;
    const int* dst = ei + E;

    auto align16 = [](size_t v) { return (v + 15) & ~(size_t)15; };
    size_t bmBytes = align16(((size_t)(n + 31) / 32) * 4);
    char* ws = (char*)d_ws;
    size_t off = 0;
    int*      deg   = (int*)(ws + off);      off += align16((size_t)n * 4);
    unsigned* bm1   = (unsigned*)(ws + off); off += bmBytes;
    unsigned* bm2   = (unsigned*)(ws + off); off += bmBytes;
    int*      cnts  = (int*)(ws + off);      off += 64;
    int*      S1    = (int*)(ws + off);      off += S1CAP * 4;
    int*      Dlist = (int*)(ws + off);      off += align16(DCAP * 4);
    unsigned long long* L2 = (unsigned long long*)(ws + off); off += (size_t)L2CAP * 8;

    // Size the cooperative grid to max co-residency (round-4 lesson: 512
    // blocks = 22% occupancy starved the latency-bound scans).
    int maxPerCU = 0;
    hipError_t oerr = hipOccupancyMaxActiveBlocksPerMultiprocessor(
        &maxPerCU, k_fused, 256, 0);
    int blocks = (oerr == hipSuccess && maxPerCU > 0) ? maxPerCU * 256 : 512;
    if (blocks > 4096) blocks = 4096;

    void* args[] = {(void*)&x, (void*)&src, (void*)&dst, (void*)&W1, (void*)&b1,
                    (void*)&W2, (void*)&b2, (void*)&Wfc, (void*)&bfc,
                    (void*)&E, (void*)&n, (void*)&deg, (void*)&bm1, (void*)&bm2,
                    (void*)&cnts, (void*)&S1, (void*)&Dlist, (void*)&L2,
                    (void*)&out};
    hipLaunchCooperativeKernel((const void*)k_fused, dim3(blocks), dim3(256),
                               args, 0, stream);
}

// Round 6
// 117.809 us; speedup vs baseline: 3.5297x; 3.5297x over previous
//
#include <hip/hip_runtime.h>

// Backward slice from the single output node n-1:
//   D = {n-1} U in-neighbors(n-1) (~34 nodes); layer-2 agg needs only edges
//   into D (~1100); deg needed only for their sources U D.
// Round-5 postmortem: cooperative grid.sync at 2048 blocks costs ~160us/sync
// (cross-XCD spin storm) -> 643us. Kernel-launch boundaries (~7-15us) are the
// CHEAPER synchronization on MI355X. So: separate launches, 5 dispatches:
//   memset: zero bm1+bm2+cnts (25KB)
//   pass1:  scan dst -> S1 multiset, bm1/Dlist (dedup, incl. tgt)
//   pass2:  scan dst w/ bm1 filter -> L2 packed list, bm2 |= sources U D,
//           lazy deg[s]=0 on first bm2 mark
//   pass3:  scan dst w/ bm2 filter -> deg atomics (~37k)
//   final:  1 block: LDS hash d->idx, per-edge msgs (independent pipelined
//           loads), g rows, layer-2 agg at tgt, FC.  (round-3's 74us version
//           was serialized dependent re-scans; this is ~3us)

#define S1CAP 2048
#define DCAP  192
#define L2CAP 65536
#define HASHSZ 512

__global__ __launch_bounds__(256)
void k_pass1(const int* __restrict__ src, const int* __restrict__ dst,
             int E4, int E, int n, int* __restrict__ cnts,
             int* __restrict__ S1, unsigned* __restrict__ bm1,
             int* __restrict__ Dlist) {
    int i = blockIdx.x * blockDim.x + threadIdx.x;
    const int tgt = n - 1;
    if (i < E4) {
        int4 d4 = ((const int4*)dst)[i];
        int dd[4] = {d4.x, d4.y, d4.z, d4.w};
#pragma unroll
        for (int k = 0; k < 4; ++k) {
            if (dd[k] == tgt) {
                int s = src[i * 4 + k];
                int p = atomicAdd(&cnts[0], 1);
                if (p < S1CAP) S1[p] = s;
                unsigned bit = 1u << (s & 31);
                unsigned old = atomicOr(&bm1[s >> 5], bit);
                if (!(old & bit)) {
                    int q = atomicAdd(&cnts[1], 1);
                    if (q < DCAP) Dlist[q] = s;
                }
            }
        }
    }
    if (i == 0) {
        for (int e = E4 * 4; e < E; ++e) {
            if (dst[e] == tgt) {
                int s = src[e];
                int p = atomicAdd(&cnts[0], 1);
                if (p < S1CAP) S1[p] = s;
                unsigned bit = 1u << (s & 31);
                unsigned old = atomicOr(&bm1[s >> 5], bit);
                if (!(old & bit)) {
                    int q = atomicAdd(&cnts[1], 1);
                    if (q < DCAP) Dlist[q] = s;
                }
            }
        }
        // tgt itself is in D (self-loop)
        unsigned bit = 1u << (tgt & 31);
        unsigned old = atomicOr(&bm1[tgt >> 5], bit);
        if (!(old & bit)) {
            int q = atomicAdd(&cnts[1], 1);
            if (q < DCAP) Dlist[q] = tgt;
        }
    }
}

__global__ __launch_bounds__(256)
void k_pass2(const int* __restrict__ src, const int* __restrict__ dst,
             int E4, int E, const unsigned* __restrict__ bm1,
             int* __restrict__ cnts, unsigned long long* __restrict__ L2,
             unsigned* __restrict__ bm2, int* __restrict__ deg,
             const int* __restrict__ Dlist) {
    int i = blockIdx.x * blockDim.x + threadIdx.x;
    // D itself into bm2 (lazy deg zero)
    if (i < DCAP) {
        int cntD = cnts[1]; if (cntD > DCAP) cntD = DCAP;
        if (i < cntD) {
            int d = Dlist[i];
            unsigned bit = 1u << (d & 31);
            unsigned old = atomicOr(&bm2[d >> 5], bit);
            if (!(old & bit)) deg[d] = 0;
        }
    }
    if (i < E4) {
        int4 d4 = ((const int4*)dst)[i];
        int dd[4] = {d4.x, d4.y, d4.z, d4.w};
#pragma unroll
        for (int k = 0; k < 4; ++k) {
            int d = dd[k];
            if ((bm1[d >> 5] >> (d & 31)) & 1u) {
                int s = src[i * 4 + k];
                int p = atomicAdd(&cnts[2], 1);
                if (p < L2CAP)
                    L2[p] = ((unsigned long long)(unsigned)d << 32) | (unsigned)s;
                unsigned bit = 1u << (s & 31);
                unsigned old = atomicOr(&bm2[s >> 5], bit);
                if (!(old & bit)) deg[s] = 0;
            }
        }
    }
    if (i == 0) {
        for (int e = E4 * 4; e < E; ++e) {
            int d = dst[e];
            if ((bm1[d >> 5] >> (d & 31)) & 1u) {
                int s = src[e];
                int p = atomicAdd(&cnts[2], 1);
                if (p < L2CAP)
                    L2[p] = ((unsigned long long)(unsigned)d << 32) | (unsigned)s;
                unsigned bit = 1u << (s & 31);
                unsigned old = atomicOr(&bm2[s >> 5], bit);
                if (!(old & bit)) deg[s] = 0;
            }
        }
    }
}

__global__ __launch_bounds__(256)
void k_pass3(const int* __restrict__ dst, int E4, int E,
             const unsigned* __restrict__ bm2, int* __restrict__ deg) {
    int i = blockIdx.x * blockDim.x + threadIdx.x;
    if (i < E4) {
        int4 d4 = ((const int4*)dst)[i];
        int dd[4] = {d4.x, d4.y, d4.z, d4.w};
#pragma unroll
        for (int k = 0; k < 4; ++k) {
            int d = dd[k];
            if ((bm2[d >> 5] >> (d & 31)) & 1u) atomicAdd(&deg[d], 1);
        }
    }
    if (i == 0) {
        for (int e = E4 * 4; e < E; ++e) {
            int d = dst[e];
            if ((bm2[d >> 5] >> (d & 31)) & 1u) atomicAdd(&deg[d], 1);
        }
    }
}

__global__ __launch_bounds__(256)
void k_final(const float* __restrict__ x, const int* __restrict__ deg,
             const int* __restrict__ cnts, const int* __restrict__ S1,
             const int* __restrict__ Dlist,
             const unsigned long long* __restrict__ L2,
             const float* __restrict__ W1, const float* __restrict__ b1,
             const float* __restrict__ W2, const float* __restrict__ b2,
             const float* __restrict__ Wfc, const float* __restrict__ bfc,
             int n, float* __restrict__ out) {
    __shared__ int hKey[HASHSZ];
    __shared__ int hVal[HASHSZ];
    __shared__ int sD[DCAP];
    __shared__ float s1D[DCAP];
    __shared__ float gD[DCAP][8];
    __shared__ float sW1[16], sb1[16], sW2[128], agg[8];

    const int tid = threadIdx.x;
    const int tgt = n - 1;
    int cnt1 = cnts[0]; if (cnt1 > S1CAP) cnt1 = S1CAP;
    int cntD = cnts[1]; if (cntD > DCAP) cntD = DCAP;
    int cnt2 = cnts[2]; if (cnt2 > L2CAP) cnt2 = L2CAP;

    for (int i = tid; i < HASHSZ; i += 256) hKey[i] = -1;
    for (int i = tid; i < cntD; i += 256) { sD[i] = Dlist[i]; s1D[i] = 0.f; }
    if (tid < 16) { sW1[tid] = W1[tid]; sb1[tid] = b1[tid]; }
    if (tid < 128) sW2[tid] = W2[tid];
    if (tid < 8) agg[tid] = 0.f;
    __syncthreads();
    // hash d -> index
    for (int i = tid; i < cntD; i += 256) {
        int d = sD[i];
        int h = d & (HASHSZ - 1);
        while (true) {
            int prev = atomicCAS(&hKey[h], -1, d);
            if (prev == -1 || prev == d) { hVal[h] = i; break; }
            h = (h + 1) & (HASHSZ - 1);
        }
    }
    __syncthreads();
    // per-edge messages -> LDS bins (independent pipelined scattered loads)
    for (int e = tid; e < cnt2; e += 256) {
        unsigned long long v = L2[e];
        int s = (int)(v & 0xffffffffu);
        int d = (int)(v >> 32);
        float msg = x[s] * rsqrtf((float)(deg[s] + 1));
        int h = d & (HASHSZ - 1);
        while (hKey[h] != d) h = (h + 1) & (HASHSZ - 1);
        atomicAdd(&s1D[hVal[h]], msg);
    }
    __syncthreads();
    // per-D-node: h1 -> g row (g = dinv_src * (h1 @ W2))
    for (int di = tid; di < cntD; di += 256) {
        int d = sD[di];
        float dv = rsqrtf((float)(deg[d] + 1));
        float t = dv * (s1D[di] + x[d] * dv);   // + self-loop term
        float g8[8] = {0, 0, 0, 0, 0, 0, 0, 0};
#pragma unroll
        for (int c = 0; c < 16; ++c) {
            float h1 = fmaxf(fmaf(t, sW1[c], sb1[c]), 0.f);
#pragma unroll
            for (int j = 0; j < 8; ++j) g8[j] = fmaf(h1, sW2[c * 8 + j], g8[j]);
        }
#pragma unroll
        for (int j = 0; j < 8; ++j) gD[di][j] = dv * g8[j];
    }
    __syncthreads();
    // layer-2 aggregation at tgt over the S1 multiset
    for (int idx = tid; idx < cnt1 * 8; idx += 256) {
        int p = idx >> 3, j = idx & 7;
        int s = S1[p];
        int h = s & (HASHSZ - 1);
        while (hKey[h] != s) h = (h + 1) & (HASHSZ - 1);
        atomicAdd(&agg[j], gD[hVal[h]][j]);
    }
    __syncthreads();
    if (tid == 0) {
        int h = tgt & (HASHSZ - 1);
        while (hKey[h] != tgt) h = (h + 1) & (HASHSZ - 1);
        int it = hVal[h];
        float dv = rsqrtf((float)(deg[tgt] + 1));
        float o = 0.f;
#pragma unroll
        for (int j = 0; j < 8; ++j)
            o += fmaxf(fmaf(dv, agg[j] + gD[it][j], b2[j]), 0.f) * Wfc[j];
        out[0] = o + bfc[0];
    }
}

extern "C" void kernel_launch(void* const* d_in, const int* in_sizes, int n_in,
                              void* d_out, int out_size, void* d_ws, size_t ws_size,
                              hipStream_t stream) {
    const float* x   = (const float*)d_in[0];
    const int*   ei  = (const int*)d_in[1];
    const float* W1  = (const float*)d_in[2];
    const float* b1  = (const float*)d_in[3];
    const float* W2  = (const float*)d_in[4];
    const float* b2  = (const float*)d_in[5];
    const float* Wfc = (const float*)d_in[6];
    const float* bfc = (const float*)d_in[7];
    float* out = (float*)d_out;

    int n = in_sizes[0];
    int E = in_sizes[1] / 2;
    const int* src = ei;
    const int* dst = ei + E;

    auto align16 = [](size_t v) { return (v + 15) & ~(size_t)15; };
    size_t bmBytes = align16(((size_t)(n + 31) / 32) * 4);
    char* ws = (char*)d_ws;
    size_t off = 0;
    unsigned* bm1   = (unsigned*)(ws + off); off += bmBytes;
    unsigned* bm2   = (unsigned*)(ws + off); off += bmBytes;
    int*      cnts  = (int*)(ws + off);      off += 64;
    size_t zeroBytes = off;                  // bm1 + bm2 + cnts (~25KB)
    int*      deg   = (int*)(ws + off);      off += align16((size_t)n * 4);
    int*      S1    = (int*)(ws + off);      off += S1CAP * 4;
    int*      Dlist = (int*)(ws + off);      off += align16(DCAP * 4);
    unsigned long long* L2 = (unsigned long long*)(ws + off); off += (size_t)L2CAP * 8;

    hipMemsetAsync(d_ws, 0, zeroBytes, stream);

    int E4 = E >> 2;
    int bE4 = (E4 + 255) / 256;

    k_pass1<<<bE4, 256, 0, stream>>>(src, dst, E4, E, n, cnts, S1, bm1, Dlist);
    k_pass2<<<bE4, 256, 0, stream>>>(src, dst, E4, E, bm1, cnts, L2, bm2, deg, Dlist);
    k_pass3<<<bE4, 256, 0, stream>>>(dst, E4, E, bm2, deg);
    k_final<<<1,   256, 0, stream>>>(x, deg, cnts, S1, Dlist, L2,
                                     W1, b1, W2, b2, Wfc, bfc, n, out);
}